// Round 8
// baseline (99.538 us; speedup 1.0000x reference)
//
#include <hip/hip_runtime.h>

#define GS   7
#define CCH  490
#define HH   128
#define WW   128
#define LDW  132        // padded row stride: spreads rows across banks, keeps 16B align
#define NB   2
#define NPAIR (CCH / 2) // 245 channel pairs per batch
#define NBLK  (NB * NPAIR)

// One block per (batch, adjacent-channel-pair). Row-prefix only (bins are
// 1..10 rows tall). Per pair: prefix ch0 -> pool ch0 (while ch1 loads are in
// flight) -> prefix ch1 -> pool ch1 -> one aligned float2 store per roi.
__global__ __launch_bounds__(512, 4) void psroi_pair(
    const float* __restrict__ rois,
    const float* __restrict__ feat,
    const int*   __restrict__ stride_p,
    float*       __restrict__ out)
{
#pragma clang fp contract(off)
    __shared__ float S[HH * LDW];   // 67,584 B -> 2 blocks/CU

    const int blk = blockIdx.x;
    const int b   = blk / NPAIR;
    const int c0  = (blk - b * NPAIR) * 2;
    const int ch0 = b * CCH + c0;
    const int tid = threadIdx.x;
    const int row = tid >> 2;       // quad of lanes shares a row
    const int sg  = tid & 3;        // 32-float column segment

    // ---- Hoisted per-RoI geometry (channel-independent), thread n = roi n ----
    const float ss = 1.0f / (float)(*stride_p);
    const int   bi = (int)rois[tid * 5 + 0];
    const float x1 = rois[tid * 5 + 1];
    const float y1 = rois[tid * 5 + 2];
    const float x2 = rois[tid * 5 + 3];
    const float y2 = rois[tid * 5 + 4];
    // exact reference op order, fp32, no contraction
    float rsw = rintf(x1) * ss;
    float rsh = rintf(y1) * ss;
    float rew = (rintf(x2) + 1.0f) * ss;
    float reh = (rintf(y2) + 1.0f) * ss;
    float rwm = (rew - rsw) * 1.3f;
    float rhm = (reh - rsh) * 1.3f;
    const float swm = (rsw + rew) * 0.5f - rwm * 0.5f;
    const float shm = (rsh + reh) * 0.5f - rhm * 0.5f;
    rwm = fmaxf(rwm, 0.1f);
    rhm = fmaxf(rhm, 0.1f);
    const float bin_h = rhm / 7.0f;
    const float bin_w = rwm / 7.0f;
    const float dh = bin_h * 0.25f;
    const float dw = bin_w * 0.25f;

    // row-prefix build from 32 raw values in regs -> S (in place, padded)
    auto build_prefix = [&](float (&u)[32]) {
        #pragma unroll
        for (int i = 1; i < 32; ++i)
            u[i] += u[i - 1];
        const float tot = u[31];
        const float t1 = __shfl_up(tot, 1, 64);
        const float t2 = __shfl_up(tot, 2, 64);
        const float t3 = __shfl_up(tot, 3, 64);
        float off = 0.0f;
        if (sg > 0) off += t1;
        if (sg > 1) off += t2;
        if (sg > 2) off += t3;
        float* rp = &S[row * LDW + sg * 32];
        #pragma unroll
        for (int i = 0; i < 8; ++i) {
            float4 q;
            q.x = u[4 * i + 0] + off; q.y = u[4 * i + 1] + off;
            q.z = u[4 * i + 2] + off; q.w = u[4 * i + 3] + off;
            *(float4*)&rp[i * 4] = q;
        }
    };

    // pool one channel from the row-prefix in S; returns this thread's value
    auto pool = [&](int c) -> float {
        if (bi != b) return 0.0f;   // value unused for other-batch rois of this block
        const int d   = c / (GS * GS);
        const int rem = c - d * (GS * GS);
        const int pi  = rem / GS;
        const int pj  = rem - pi * GS;
        const float gi = (float)pi;
        const float gj = (float)pj;
        const int hs  = (int)fminf(fmaxf(floorf(shm + gi * bin_h - dh),          0.0f), 128.0f);
        const int he  = (int)fminf(fmaxf(ceilf (shm + (gi + 1.0f) * bin_h + dh), 0.0f), 128.0f);
        const int ws2 = (int)fminf(fmaxf(floorf(swm + gj * bin_w - dw),          0.0f), 128.0f);
        const int we  = (int)fminf(fmaxf(ceilf (swm + (gj + 1.0f) * bin_w + dw), 0.0f), 128.0f);
        const int area = (he - hs) * (we - ws2);
        float total = 0.0f;
        if (area > 0) {
            if (ws2 > 0) {
                for (int r = hs; r < he; ++r)
                    total += S[r * LDW + (we - 1)] - S[r * LDW + (ws2 - 1)];
            } else {
                for (int r = hs; r < he; ++r)
                    total += S[r * LDW + (we - 1)];
            }
        }
        return (area > 0) ? (total / (float)area) : 0.0f;
    };

    // ---- channel 0: load + prefix ----
    float u[32];
    {
        const float* __restrict__ fp = feat + (size_t)ch0 * (HH * WW) + row * WW + sg * 32;
        #pragma unroll
        for (int i = 0; i < 8; ++i) {
            const float4 q = *(const float4*)&fp[i * 4];
            u[4 * i + 0] = q.x; u[4 * i + 1] = q.y;
            u[4 * i + 2] = q.z; u[4 * i + 3] = q.w;
        }
        build_prefix(u);
    }
    __syncthreads();                       // B1: prefix(ch0) visible

    // ---- channel 1 loads issued BEFORE pooling ch0 (VMEM overlaps DS) ----
    {
        const float* __restrict__ fp = feat + (size_t)(ch0 + 1) * (HH * WW) + row * WW + sg * 32;
        #pragma unroll
        for (int i = 0; i < 8; ++i) {
            const float4 q = *(const float4*)&fp[i * 4];
            u[4 * i + 0] = q.x; u[4 * i + 1] = q.y;
            u[4 * i + 2] = q.z; u[4 * i + 3] = q.w;
        }
    }

    const float v0 = pool(c0);             // reads S while ch1 loads are in flight
    __syncthreads();                       // B2: all pool(ch0) reads done -> S reusable

    build_prefix(u);
    __syncthreads();                       // B3: prefix(ch1) visible

    const float v1 = pool(c0 + 1);

    if (bi == b) {                         // one aligned float2 store per roi
        float2 o; o.x = v0; o.y = v1;
        *(float2*)&out[(size_t)tid * CCH + c0] = o;
    }
}

extern "C" void kernel_launch(void* const* d_in, const int* in_sizes, int n_in,
                              void* d_out, int out_size, void* d_ws, size_t ws_size,
                              hipStream_t stream)
{
    const float* rois     = (const float*)d_in[0];
    const float* feat     = (const float*)d_in[1];
    const int*   stride_p = (const int*)d_in[2];
    float*       out      = (float*)d_out;

    dim3 grid(NBLK);    // 490 blocks: one per (batch, channel pair)
    dim3 block(512);
    hipLaunchKernelGGL(psroi_pair, grid, block, 0, stream, rois, feat, stride_p, out);
}